// Round 5
// baseline (264.505 us; speedup 1.0000x reference)
//
#include <hip/hip_runtime.h>
#include <hip/hip_bf16.h>

// ---------------------------------------------------------------------------
// NattenBlock fused mega-kernel. 2048 pixels (2x32x32), d_model 768,
// 7x7 NATTEN, GQA 12q/4kv, D=64.
// Round 5: single persistent kernel (384 blocks), phases separated by
// device-scope spin barriers (monotonic counter). P0 fp32->bf16 convert,
// P1 qkv GEMM (64x64/BK=128, LDS double-buffered), P2 natten MFMA,
// P3 out GEMM. Co-residency guaranteed: 64KB LDS + launch_bounds(256,2)
// -> >=2 blocks/CU capacity (512 >= 384 grid).
// ---------------------------------------------------------------------------

typedef __attribute__((ext_vector_type(8))) __bf16 bf16x8;
typedef __attribute__((ext_vector_type(4))) float floatx4;
typedef unsigned short u16;

#define GRID 384

__device__ inline u16 f2bf(float f) {
    union { float f; unsigned u; } v; v.f = f;
    return (u16)((v.u + 0x7fff + ((v.u >> 16) & 1)) >> 16);   // RNE
}

__device__ inline void gl_lds16(const void* g, void* l) {
    __builtin_amdgcn_global_load_lds(
        (const __attribute__((address_space(1))) void*)g,
        (__attribute__((address_space(3))) void*)l, 16, 0, 0);
}

struct SmemG { u16 As[2 * 8192]; u16 Bs[2 * 8192]; };            // 64 KB
struct SmemN { u16 Ks[224 * 72]; u16 Vs[64 * 224]; u16 Pw[2048]; }; // 65024 B
union Smem { SmemG g; SmemN n; };

// Device-scope grid barrier: monotonic counter, target = phase * GRID.
__device__ inline void gridbar(unsigned* cnt, unsigned target) {
    __syncthreads();
    if (threadIdx.x == 0) {
        __threadfence();                       // release prior writes
        atomicAdd(cnt, 1u);
        while (__hip_atomic_load(cnt, __ATOMIC_ACQUIRE,
                                 __HIP_MEMORY_SCOPE_AGENT) < target)
            __builtin_amdgcn_s_sleep(2);
        __threadfence();                       // acquire
    }
    __syncthreads();
}

// One 64x64 GEMM-NT tile, bf16 in / fp32 accum, BK=128 double-buffered.
// MODE 0: fp32 C[M,N]. MODE 1 (qkv): col<1024 -> bf16 Cb[row*1024+col];
// col>=1024 -> transposed bf16 vT[(col-1024)*2048 + row].
template<int MODE>
__device__ __forceinline__ void gemm_tile(
    const u16* __restrict__ A, const u16* __restrict__ B,
    float* __restrict__ C, u16* __restrict__ Cb, u16* __restrict__ vT,
    int bm, int bn, int N, int K, SmemG& sm)
{
    const int tid = threadIdx.x;
    const int lane = tid & 63;
    const int wave = tid >> 6;
    const int qr = (wave >> 1) * 32;
    const int qc = (wave & 1) * 32;

    floatx4 acc[2][2] = {};

    // Staging roles: waves 0,1 -> As (16 chunks of 1KB), waves 2,3 -> Bs.
    const bool isA = wave < 2;
    const int  half = wave & 1;
    const int  l2 = lane >> 2;         // row within 16-row group
    const int  l3 = (lane & 3) * 8;    // k offset (u16)
    const u16* Xsrc = isA ? A : B;
    const int  bx   = isA ? bm : bn;
    u16* Xlds = isA ? sm.As : sm.Bs;
    int gofs[8], lofs[8];
    #pragma unroll
    for (int cc = 0; cc < 8; cc++) {
        int c = half * 8 + cc, kc = c & 3, rg = c >> 2;
        gofs[cc] = (bx + rg * 16 + l2) * K + kc * 32 + l3;
        lofs[cc] = kc * 2048 + rg * 512;
    }

    const int fr = lane & 15;
    const int fk = (lane >> 4) * 8;
    const int nk = K >> 7;             // K/128

    // stage iter 0 -> buf 0
    #pragma unroll
    for (int cc = 0; cc < 8; cc++)
        gl_lds16(Xsrc + gofs[cc], Xlds + lofs[cc]);

    for (int it = 0; it < nk; it++) {
        const int buf = (it & 1) * 8192;
        __syncthreads();                       // buf ready (vmcnt drain)
        if (it + 1 < nk) {
            const int nbuf = (~it & 1) * 8192;
            #pragma unroll
            for (int cc = 0; cc < 8; cc++)
                gl_lds16(Xsrc + gofs[cc] + (it + 1) * 128, Xlds + nbuf + lofs[cc]);
        }
        #pragma unroll
        for (int kc = 0; kc < 4; kc++) {
            bf16x8 af0 = *(const bf16x8*)&sm.As[buf + kc * 2048 + (qr +      fr) * 32 + fk];
            bf16x8 af1 = *(const bf16x8*)&sm.As[buf + kc * 2048 + (qr + 16 + fr) * 32 + fk];
            bf16x8 bf0 = *(const bf16x8*)&sm.Bs[buf + kc * 2048 + (qc +      fr) * 32 + fk];
            bf16x8 bf1 = *(const bf16x8*)&sm.Bs[buf + kc * 2048 + (qc + 16 + fr) * 32 + fk];
            acc[0][0] = __builtin_amdgcn_mfma_f32_16x16x32_bf16(af0, bf0, acc[0][0], 0, 0, 0);
            acc[0][1] = __builtin_amdgcn_mfma_f32_16x16x32_bf16(af0, bf1, acc[0][1], 0, 0, 0);
            acc[1][0] = __builtin_amdgcn_mfma_f32_16x16x32_bf16(af1, bf0, acc[1][0], 0, 0, 0);
            acc[1][1] = __builtin_amdgcn_mfma_f32_16x16x32_bf16(af1, bf1, acc[1][1], 0, 0, 0);
        }
    }

    // C/D layout: col = lane&15, row = (lane>>4)*4 + r.
    const int cr = (lane >> 4) * 4;
    const int ccol = lane & 15;
    #pragma unroll
    for (int i = 0; i < 2; i++) {
        #pragma unroll
        for (int j = 0; j < 2; j++) {
            const int row0 = bm + qr + i * 16 + cr;
            const int col  = bn + qc + j * 16 + ccol;
            if (MODE == 0) {
                #pragma unroll
                for (int r = 0; r < 4; r++)
                    C[(size_t)(row0 + r) * N + col] = acc[i][j][r];
            } else {
                if (col < 1024) {
                    #pragma unroll
                    for (int r = 0; r < 4; r++)
                        Cb[(size_t)(row0 + r) * 1024 + col] = f2bf(acc[i][j][r]);
                } else {
                    ushort4 w;
                    w.x = f2bf(acc[i][j][0]); w.y = f2bf(acc[i][j][1]);
                    w.z = f2bf(acc[i][j][2]); w.w = f2bf(acc[i][j][3]);
                    *(ushort4*)&vT[(size_t)(col - 1024) * 2048 + row0] = w;
                }
            }
        }
    }
}

// NATTEN 7x7 MFMA tile: (q-head h, 8x8 pixel tile). 4 waves x 16 queries.
__device__ __forceinline__ void natten_tile(
    const u16* __restrict__ qkv, const u16* __restrict__ vT,
    u16* __restrict__ o, int h, int tb, SmemN& sm)
{
    const int g  = h & 3;
    const int batch = tb >> 4;
    const int ti = ((tb >> 2) & 3) * 8;
    const int tj = (tb & 3) * 8;
    const int wu_i = min(max(ti - 3, 0), 18);
    const int wu_j = min(max(tj - 3, 0), 18);
    const int tid = threadIdx.x, lane = tid & 63, wave = tid >> 6;
    const int pixbase = batch << 10;

    // K rows: n = a*16+b, b clamped to 13 for pad cols (masked later).
    for (int c = tid; c < 1792; c += 256) {
        int n = c >> 3, seg = (c & 7) * 8;
        int a = n >> 4, b = min(n & 15, 13);
        int pix = pixbase + (wu_i + a) * 32 + wu_j + b;
        *(uint4*)&sm.Ks[n * 72 + seg] =
            *(const uint4*)&qkv[(size_t)pix * 1024 + 768 + g * 64 + seg];
    }
    // V^T[d][n]: wave -> 16 d's; lane: b = lane&15, a = (lane>>4)+4*rr.
    {
        const int b  = lane & 15;
        const int ar = lane >> 4;
        bool vok[4]; int voff[4];
        #pragma unroll
        for (int rr = 0; rr < 4; rr++) {
            int a = ar + rr * 4;
            vok[rr]  = (a < 14) && (b < 14);
            voff[rr] = (wu_i + a) * 32 + wu_j + b;
        }
        const u16* vsrc = &vT[(size_t)(g * 64 + wave * 16) * 2048 + pixbase];
        #pragma unroll 4
        for (int dd = 0; dd < 16; dd++) {
            #pragma unroll
            for (int rr = 0; rr < 4; rr++) {
                int a = ar + rr * 4;
                if (a < 14)
                    sm.Vs[(wave * 16 + dd) * 224 + rr * 64 + lane] =
                        vok[rr] ? vsrc[voff[rr]] : (u16)0;
            }
            vsrc += 2048;
        }
    }
    __syncthreads();

    const int fr = lane & 15;
    const int fk = (lane >> 4) * 8;

    bf16x8 aq0, aq1;
    {
        int qq = wave * 16 + fr;
        int pixq = pixbase + (ti + (qq >> 3)) * 32 + tj + (qq & 7);
        const u16* qp = &qkv[(size_t)pixq * 1024 + h * 64];
        aq0 = *(const bf16x8*)(qp + fk);
        aq1 = *(const bf16x8*)(qp + 32 + fk);
    }

    bool colok[4]; int tlo[4], thi[4];
    #pragma unroll
    for (int r = 0; r < 4; r++) {
        int qq = wave * 16 + (lane >> 4) * 4 + r;
        int qi = ti + (qq >> 3), qj = tj + (qq & 7);
        int si = min(max(qi - 3, 0), 25);
        int sj = min(max(qj - 3, 0), 25);
        colok[r] = (fr < 14) && (wu_j + fr >= sj) && (wu_j + fr <= sj + 6);
        tlo[r] = si - wu_i; thi[r] = tlo[r] + 6;
    }

    float s[14][4];
    float mx[4] = {-1e30f, -1e30f, -1e30f, -1e30f};
    #pragma unroll
    for (int t = 0; t < 14; t++) {
        bf16x8 bk0 = *(const bf16x8*)&sm.Ks[(t * 16 + fr) * 72 + fk];
        bf16x8 bk1 = *(const bf16x8*)&sm.Ks[(t * 16 + fr) * 72 + 32 + fk];
        floatx4 a4 = {};
        a4 = __builtin_amdgcn_mfma_f32_16x16x32_bf16(aq0, bk0, a4, 0, 0, 0);
        a4 = __builtin_amdgcn_mfma_f32_16x16x32_bf16(aq1, bk1, a4, 0, 0, 0);
        #pragma unroll
        for (int r = 0; r < 4; r++) {
            bool v = colok[r] && (t >= tlo[r]) && (t <= thi[r]);
            s[t][r] = v ? a4[r] * 0.125f : -1e30f;
            mx[r] = fmaxf(mx[r], s[t][r]);
        }
    }
    #pragma unroll
    for (int r = 0; r < 4; r++) {
        mx[r] = fmaxf(mx[r], __shfl_xor(mx[r], 1));
        mx[r] = fmaxf(mx[r], __shfl_xor(mx[r], 2));
        mx[r] = fmaxf(mx[r], __shfl_xor(mx[r], 4));
        mx[r] = fmaxf(mx[r], __shfl_xor(mx[r], 8));
    }
    float l[4] = {0.f, 0.f, 0.f, 0.f};
    #pragma unroll
    for (int t = 0; t < 14; t++)
        #pragma unroll
        for (int r = 0; r < 4; r++) {
            float p = __expf(s[t][r] - mx[r]);
            s[t][r] = p; l[r] += p;
        }
    #pragma unroll
    for (int r = 0; r < 4; r++) {
        l[r] += __shfl_xor(l[r], 1);
        l[r] += __shfl_xor(l[r], 2);
        l[r] += __shfl_xor(l[r], 4);
        l[r] += __shfl_xor(l[r], 8);
    }
    float rinv[4];
    #pragma unroll
    for (int r = 0; r < 4; r++) rinv[r] = 1.0f / l[r];

    u16* pw = &sm.Pw[wave * 512];
    floatx4 oacc[4] = {};
    #pragma unroll
    for (int kc = 0; kc < 7; kc++) {
        #pragma unroll
        for (int tt = 0; tt < 2; tt++) {
            int t = kc * 2 + tt;
            #pragma unroll
            for (int r = 0; r < 4; r++)
                pw[((lane >> 4) * 4 + r) * 32 + tt * 16 + fr] =
                    f2bf(s[t][r] * rinv[r]);
        }
        bf16x8 bp = *(const bf16x8*)&pw[fr * 32 + fk];
        #pragma unroll
        for (int u = 0; u < 4; u++) {
            bf16x8 av = *(const bf16x8*)&sm.Vs[(u * 16 + fr) * 224 + kc * 32 + fk];
            oacc[u] = __builtin_amdgcn_mfma_f32_16x16x32_bf16(av, bp, oacc[u], 0, 0, 0);
        }
    }

    {
        int qq = wave * 16 + fr;
        int pixq = pixbase + (ti + (qq >> 3)) * 32 + tj + (qq & 7);
        u16* op = &o[(size_t)pixq * 768 + h * 64];
        #pragma unroll
        for (int u = 0; u < 4; u++) {
            ushort4 w;
            w.x = f2bf(oacc[u][0]); w.y = f2bf(oacc[u][1]);
            w.z = f2bf(oacc[u][2]); w.w = f2bf(oacc[u][3]);
            *(ushort4*)(op + u * 16 + (lane >> 4) * 4) = w;
        }
    }
}

__global__ __launch_bounds__(256, 2) void mega_kernel(
    const float* __restrict__ x, const float* __restrict__ w1,
    const float* __restrict__ w2,
    u16* __restrict__ xb, u16* __restrict__ w1b, u16* __restrict__ w2b,
    u16* __restrict__ qkvb, u16* __restrict__ vTb, u16* __restrict__ ob,
    float* __restrict__ out, unsigned* __restrict__ bar)
{
    __shared__ Smem sm;
    const int bid = blockIdx.x;
    const int tid = threadIdx.x;

    // ---- P0: fp32 -> bf16 convert (786432 float4 total, 8 per thread).
    {
        int base = bid * 2048 + tid;
        #pragma unroll
        for (int i = 0; i < 8; i++) {
            int t = base + i * 256;
            const float* s; u16* d;
            if (t < 393216)      { s = x;  d = xb; }
            else if (t < 638976) { s = w1; d = w1b; t -= 393216; }
            else                 { s = w2; d = w2b; t -= 638976; }
            float4 v = ((const float4*)s)[t];
            ushort4 o;
            o.x = f2bf(v.x); o.y = f2bf(v.y); o.z = f2bf(v.z); o.w = f2bf(v.w);
            ((ushort4*)d)[t] = o;
        }
    }
    gridbar(bar, 1 * GRID);

    // ---- P1: qkv GEMM, 640 tiles (20 x-tiles of N=1280, 32 y-tiles).
    for (int t = bid; t < 640; t += GRID) {
        int bn = (t % 20) * 64, bm = (t / 20) * 64;
        gemm_tile<1>(xb, w1b, nullptr, qkvb, vTb, bm, bn, 1280, 768, sm.g);
    }
    gridbar(bar, 2 * GRID);

    // ---- P2: natten, 384 tiles (12 heads x 32 pixel-tiles).
    natten_tile(qkvb, vTb, ob, bid % 12, bid / 12, sm.n);
    gridbar(bar, 3 * GRID);

    // ---- P3: out GEMM, 384 tiles (12 x-tiles of N=768, 32 y-tiles).
    {
        int bn = (bid % 12) * 64, bm = (bid / 12) * 64;
        gemm_tile<0>(ob, w2b, out, nullptr, nullptr, bm, bn, 768, 768, sm.g);
    }
}

extern "C" void kernel_launch(void* const* d_in, const int* in_sizes, int n_in,
                              void* d_out, int out_size, void* d_ws, size_t ws_size,
                              hipStream_t stream)
{
    const float* x     = (const float*)d_in[0];   // (2048, 768)
    const float* w_qkv = (const float*)d_in[1];   // (1280, 768)
    const float* w_out = (const float*)d_in[2];   // (768, 768)
    float* out = (float*)d_out;                   // (2048, 768) fp32

    char* ws = (char*)d_ws;
    unsigned* bar = (unsigned*)ws; ws += 256;                // barrier counter
    u16* qkvb = (u16*)ws; ws += (size_t)2048 * 1024 * 2;     // q|k bf16, 4 MB
    u16* vTb  = (u16*)ws; ws += (size_t)256 * 2048 * 2;      // v^T bf16, 1 MB
    u16* xb   = (u16*)ws; ws += (size_t)2048 * 768 * 2;      // 3 MB
    u16* w1b  = (u16*)ws; ws += (size_t)1280 * 768 * 2;      // 2 MB
    u16* w2b  = (u16*)ws; ws += (size_t)768 * 768 * 2;       // 1.1 MB
    u16* ob   = (u16*)ws;                                    // 3 MB

    hipMemsetAsync(bar, 0, 8, stream);   // zero barrier counter (capturable)
    mega_kernel<<<dim3(GRID), dim3(256), 0, stream>>>(
        x, w_qkv, w_out, xb, w1b, w2b, qkvb, vTb, ob, out, bar);
}

// Round 6
// 121.215 us; speedup vs baseline: 2.1821x; 2.1821x over previous
//
#include <hip/hip_runtime.h>
#include <hip/hip_bf16.h>

// ---------------------------------------------------------------------------
// NattenBlock: qkv GEMM -> 7x7 NATTEN (GQA 12q/4kv, D=64) -> out GEMM.
// 2048 pixels (2x32x32), d_model 768.
// Round 6: back to split kernels (grid barriers cost ~65us each on MI355X —
// round 5 post-mortem). 3 dispatches: convert folded into GEMM staging
// (fp32 global -> regs -> bf16 -> ds_write_b128), register-pipelined K-loop
// (next iter's loads issued before MFMA, overlapping compute).
// ---------------------------------------------------------------------------

typedef __attribute__((ext_vector_type(8))) __bf16 bf16x8;
typedef __attribute__((ext_vector_type(4))) float floatx4;
typedef unsigned short u16;

__device__ inline u16 f2bf(float f) {
    union { float f; unsigned u; } v; v.f = f;
    return (u16)((v.u + 0x7fff + ((v.u >> 16) & 1)) >> 16);   // RNE
}

// C = A[M,K] @ B[N,K]^T, fp32 accum. Tile 64Mx64N, BK=128 as 4 kc sub-tiles
// of [64][32] bf16. 256 thr = 4 waves: waves 0,1 stage A, waves 2,3 stage B.
// Staging thread (t = tid&127): kp = t&15 (k-oct of 8 elems), rowg = t>>4
// (8 rows). Per iter: 8 rows x 8 k-elems -> one ds_write_b128 each.
// MODE 1 (qkv GEMM): A = x fp32; epilogue col<1024 -> bf16 Cb[row*1024+col],
//   col>=1024 -> transposed bf16 vT[(col-1024)*2048+row].
// MODE 0 (out GEMM): A = bf16 attention output; epilogue fp32 C[M,N].
template<int MODE>
__global__ __launch_bounds__(256) void gemm_fused(
    const void* __restrict__ Ain, const float* __restrict__ Bf,
    float* __restrict__ C, u16* __restrict__ Cb, u16* __restrict__ vT,
    int N, int K)
{
    __shared__ __align__(16) u16 As[4 * 64 * 32];   // 16 KB [kc][row][32]
    __shared__ __align__(16) u16 Bs[4 * 64 * 32];   // 16 KB
    const int tid = threadIdx.x;
    const int lane = tid & 63;
    const int wave = tid >> 6;
    const int bm = blockIdx.y * 64;
    const int bn = blockIdx.x * 64;
    const int qr = (wave >> 1) * 32;
    const int qc = (wave & 1) * 32;

    floatx4 acc[2][2] = {};

    // ---- staging role setup
    const bool roleA = (wave < 2);
    const int t = tid & 127;
    const int kp = t & 15;            // k-oct: elems [kp*8, kp*8+8)
    const int rowg = t >> 4;          // rows rowg*8 .. +8
    const int bx = roleA ? bm : bn;
    u16* ldst = (roleA ? As : Bs) + (kp >> 2) * 2048 + (kp & 3) * 8;
    const bool a_is_bf16 = (MODE == 0) && roleA;
    const u16*   Xb = (const u16*)Ain;                      // MODE0 A
    const float* Xf = roleA ? (const float*)Ain : Bf;       // fp32 src

    float4 rf[8][2];   // fp32 staging regs
    uint4  rb[8];      // bf16 staging regs (MODE0 A)

    auto load_step = [&](int k0) {
        if (a_is_bf16) {
            #pragma unroll
            for (int rr = 0; rr < 8; rr++)
                rb[rr] = *(const uint4*)&Xb[(size_t)(bx + rowg * 8 + rr) * K + k0 + kp * 8];
        } else {
            #pragma unroll
            for (int rr = 0; rr < 8; rr++) {
                const float* p = &Xf[(size_t)(bx + rowg * 8 + rr) * K + k0 + kp * 8];
                rf[rr][0] = *(const float4*)p;
                rf[rr][1] = *(const float4*)(p + 4);
            }
        }
    };
    auto store_step = [&]() {
        if (a_is_bf16) {
            #pragma unroll
            for (int rr = 0; rr < 8; rr++)
                *(uint4*)&ldst[(rowg * 8 + rr) * 32] = rb[rr];
        } else {
            #pragma unroll
            for (int rr = 0; rr < 8; rr++) {
                union { u16 s[8]; uint4 v; } pk;
                pk.s[0] = f2bf(rf[rr][0].x); pk.s[1] = f2bf(rf[rr][0].y);
                pk.s[2] = f2bf(rf[rr][0].z); pk.s[3] = f2bf(rf[rr][0].w);
                pk.s[4] = f2bf(rf[rr][1].x); pk.s[5] = f2bf(rf[rr][1].y);
                pk.s[6] = f2bf(rf[rr][1].z); pk.s[7] = f2bf(rf[rr][1].w);
                *(uint4*)&ldst[(rowg * 8 + rr) * 32] = pk.v;
            }
        }
    };

    const int fr = lane & 15;
    const int fk = (lane >> 4) * 8;
    const int nk = K >> 7;            // K/128

    load_step(0);
    for (int it = 0; it < nk; it++) {
        store_step();
        __syncthreads();              // LDS tile complete
        if (it + 1 < nk)
            load_step((it + 1) * 128);   // overlaps with MFMA below
        #pragma unroll
        for (int kc = 0; kc < 4; kc++) {
            bf16x8 af0 = *(const bf16x8*)&As[kc * 2048 + (qr +      fr) * 32 + fk];
            bf16x8 af1 = *(const bf16x8*)&As[kc * 2048 + (qr + 16 + fr) * 32 + fk];
            bf16x8 bf0 = *(const bf16x8*)&Bs[kc * 2048 + (qc +      fr) * 32 + fk];
            bf16x8 bf1 = *(const bf16x8*)&Bs[kc * 2048 + (qc + 16 + fr) * 32 + fk];
            acc[0][0] = __builtin_amdgcn_mfma_f32_16x16x32_bf16(af0, bf0, acc[0][0], 0, 0, 0);
            acc[0][1] = __builtin_amdgcn_mfma_f32_16x16x32_bf16(af0, bf1, acc[0][1], 0, 0, 0);
            acc[1][0] = __builtin_amdgcn_mfma_f32_16x16x32_bf16(af1, bf0, acc[1][0], 0, 0, 0);
            acc[1][1] = __builtin_amdgcn_mfma_f32_16x16x32_bf16(af1, bf1, acc[1][1], 0, 0, 0);
        }
        __syncthreads();              // all waves done reading LDS
    }

    // C/D layout: col = lane&15, row = (lane>>4)*4 + r.
    const int cr = (lane >> 4) * 4;
    const int ccol = lane & 15;
    #pragma unroll
    for (int i = 0; i < 2; i++) {
        #pragma unroll
        for (int j = 0; j < 2; j++) {
            const int row0 = bm + qr + i * 16 + cr;
            const int col  = bn + qc + j * 16 + ccol;
            if (MODE == 0) {
                #pragma unroll
                for (int r = 0; r < 4; r++)
                    C[(size_t)(row0 + r) * N + col] = acc[i][j][r];
            } else {
                if (col < 1024) {
                    #pragma unroll
                    for (int r = 0; r < 4; r++)
                        Cb[(size_t)(row0 + r) * 1024 + col] = f2bf(acc[i][j][r]);
                } else {
                    ushort4 w;
                    w.x = f2bf(acc[i][j][0]); w.y = f2bf(acc[i][j][1]);
                    w.z = f2bf(acc[i][j][2]); w.w = f2bf(acc[i][j][3]);
                    *(ushort4*)&vT[(size_t)(col - 1024) * 2048 + row0] = w;
                }
            }
        }
    }
}

// NATTEN 7x7 MFMA. Block = (q-head h, 8x8 pixel tile). 4 waves x 16 queries.
// KV union = 14x14 patch at wu = clip(tile-3, 0, 18); n = a*16+b, masked.
__global__ __launch_bounds__(256) void natten_mfma(
    const u16* __restrict__ qkv, const u16* __restrict__ vT,
    u16* __restrict__ o)
{
    __shared__ __align__(16) u16 Ks[224 * 72];
    __shared__ __align__(16) u16 Vs[64 * 224];
    __shared__ __align__(16) u16 Pw[4 * 512];
    const int h  = blockIdx.x;        // 0..11
    const int tb = blockIdx.y;        // 0..31
    const int g  = h & 3;
    const int batch = tb >> 4;
    const int ti = ((tb >> 2) & 3) * 8;
    const int tj = (tb & 3) * 8;
    const int wu_i = min(max(ti - 3, 0), 18);
    const int wu_j = min(max(tj - 3, 0), 18);
    const int tid = threadIdx.x, lane = tid & 63, wave = tid >> 6;
    const int pixbase = batch << 10;

    for (int c = tid; c < 1792; c += 256) {
        int n = c >> 3, seg = (c & 7) * 8;
        int a = n >> 4, b = min(n & 15, 13);
        int pix = pixbase + (wu_i + a) * 32 + wu_j + b;
        *(uint4*)&Ks[n * 72 + seg] =
            *(const uint4*)&qkv[(size_t)pix * 1024 + 768 + g * 64 + seg];
    }
    {
        const int b  = lane & 15;
        const int ar = lane >> 4;
        bool vok[4]; int voff[4];
        #pragma unroll
        for (int rr = 0; rr < 4; rr++) {
            int a = ar + rr * 4;
            vok[rr]  = (a < 14) && (b < 14);
            voff[rr] = (wu_i + a) * 32 + wu_j + b;
        }
        const u16* vsrc = &vT[(size_t)(g * 64 + wave * 16) * 2048 + pixbase];
        #pragma unroll 4
        for (int dd = 0; dd < 16; dd++) {
            #pragma unroll
            for (int rr = 0; rr < 4; rr++) {
                int a = ar + rr * 4;
                if (a < 14)
                    Vs[(wave * 16 + dd) * 224 + rr * 64 + lane] =
                        vok[rr] ? vsrc[voff[rr]] : (u16)0;
            }
            vsrc += 2048;
        }
    }
    __syncthreads();

    const int fr = lane & 15;
    const int fk = (lane >> 4) * 8;

    bf16x8 aq0, aq1;
    {
        int qq = wave * 16 + fr;
        int pixq = pixbase + (ti + (qq >> 3)) * 32 + tj + (qq & 7);
        const u16* qp = &qkv[(size_t)pixq * 1024 + h * 64];
        aq0 = *(const bf16x8*)(qp + fk);
        aq1 = *(const bf16x8*)(qp + 32 + fk);
    }

    bool colok[4]; int tlo[4], thi[4];
    #pragma unroll
    for (int r = 0; r < 4; r++) {
        int qq = wave * 16 + (lane >> 4) * 4 + r;
        int qi = ti + (qq >> 3), qj = tj + (qq & 7);
        int si = min(max(qi - 3, 0), 25);
        int sj = min(max(qj - 3, 0), 25);
        colok[r] = (fr < 14) && (wu_j + fr >= sj) && (wu_j + fr <= sj + 6);
        tlo[r] = si - wu_i; thi[r] = tlo[r] + 6;
    }

    float s[14][4];
    float mx[4] = {-1e30f, -1e30f, -1e30f, -1e30f};
    #pragma unroll
    for (int t = 0; t < 14; t++) {
        bf16x8 bk0 = *(const bf16x8*)&Ks[(t * 16 + fr) * 72 + fk];
        bf16x8 bk1 = *(const bf16x8*)&Ks[(t * 16 + fr) * 72 + 32 + fk];
        floatx4 a4 = {};
        a4 = __builtin_amdgcn_mfma_f32_16x16x32_bf16(aq0, bk0, a4, 0, 0, 0);
        a4 = __builtin_amdgcn_mfma_f32_16x16x32_bf16(aq1, bk1, a4, 0, 0, 0);
        #pragma unroll
        for (int r = 0; r < 4; r++) {
            bool v = colok[r] && (t >= tlo[r]) && (t <= thi[r]);
            s[t][r] = v ? a4[r] * 0.125f : -1e30f;
            mx[r] = fmaxf(mx[r], s[t][r]);
        }
    }
    #pragma unroll
    for (int r = 0; r < 4; r++) {
        mx[r] = fmaxf(mx[r], __shfl_xor(mx[r], 1));
        mx[r] = fmaxf(mx[r], __shfl_xor(mx[r], 2));
        mx[r] = fmaxf(mx[r], __shfl_xor(mx[r], 4));
        mx[r] = fmaxf(mx[r], __shfl_xor(mx[r], 8));
    }
    float l[4] = {0.f, 0.f, 0.f, 0.f};
    #pragma unroll
    for (int t = 0; t < 14; t++)
        #pragma unroll
        for (int r = 0; r < 4; r++) {
            float p = __expf(s[t][r] - mx[r]);
            s[t][r] = p; l[r] += p;
        }
    #pragma unroll
    for (int r = 0; r < 4; r++) {
        l[r] += __shfl_xor(l[r], 1);
        l[r] += __shfl_xor(l[r], 2);
        l[r] += __shfl_xor(l[r], 4);
        l[r] += __shfl_xor(l[r], 8);
    }
    float rinv[4];
    #pragma unroll
    for (int r = 0; r < 4; r++) rinv[r] = 1.0f / l[r];

    u16* pw = &Pw[wave * 512];
    floatx4 oacc[4] = {};
    #pragma unroll
    for (int kc = 0; kc < 7; kc++) {
        #pragma unroll
        for (int tt = 0; tt < 2; tt++) {
            int t = kc * 2 + tt;
            #pragma unroll
            for (int r = 0; r < 4; r++)
                pw[((lane >> 4) * 4 + r) * 32 + tt * 16 + fr] =
                    f2bf(s[t][r] * rinv[r]);
        }
        bf16x8 bp = *(const bf16x8*)&pw[fr * 32 + fk];
        #pragma unroll
        for (int u = 0; u < 4; u++) {
            bf16x8 av = *(const bf16x8*)&Vs[(u * 16 + fr) * 224 + kc * 32 + fk];
            oacc[u] = __builtin_amdgcn_mfma_f32_16x16x32_bf16(av, bp, oacc[u], 0, 0, 0);
        }
    }

    {
        int qq = wave * 16 + fr;
        int pixq = pixbase + (ti + (qq >> 3)) * 32 + tj + (qq & 7);
        u16* op = &o[(size_t)pixq * 768 + h * 64];
        #pragma unroll
        for (int u = 0; u < 4; u++) {
            ushort4 w;
            w.x = f2bf(oacc[u][0]); w.y = f2bf(oacc[u][1]);
            w.z = f2bf(oacc[u][2]); w.w = f2bf(oacc[u][3]);
            *(ushort4*)(op + u * 16 + (lane >> 4) * 4) = w;
        }
    }
}

extern "C" void kernel_launch(void* const* d_in, const int* in_sizes, int n_in,
                              void* d_out, int out_size, void* d_ws, size_t ws_size,
                              hipStream_t stream)
{
    const float* x     = (const float*)d_in[0];   // (2048, 768)
    const float* w_qkv = (const float*)d_in[1];   // (1280, 768)
    const float* w_out = (const float*)d_in[2];   // (768, 768)
    float* out = (float*)d_out;                   // (2048, 768) fp32

    char* ws = (char*)d_ws;
    u16* qkvb = (u16*)ws; ws += (size_t)2048 * 1024 * 2;   // q|k bf16, 4 MB
    u16* vTb  = (u16*)ws; ws += (size_t)256 * 2048 * 2;    // v^T bf16, 1 MB
    u16* ob   = (u16*)ws;                                  // attn out, 3 MB

    // 1) qkv = x @ w_qkv^T  (fp32 in, inline bf16 convert, MFMA)
    gemm_fused<1><<<dim3(1280 / 64, 2048 / 64), dim3(256), 0, stream>>>(
        x, w_qkv, nullptr, qkvb, vTb, 1280, 768);
    // 2) neighborhood attention
    natten_mfma<<<dim3(12, 32), dim3(256), 0, stream>>>(qkvb, vTb, ob);
    // 3) out = o @ w_out^T  (A bf16, B fp32 inline convert)
    gemm_fused<0><<<dim3(768 / 64, 2048 / 64), dim3(256), 0, stream>>>(
        ob, w_out, out, nullptr, nullptr, 768, 768);
}

// Round 7
// 111.865 us; speedup vs baseline: 2.3645x; 1.0836x over previous
//
#include <hip/hip_runtime.h>
#include <hip/hip_bf16.h>

// ---------------------------------------------------------------------------
// NattenBlock: qkv GEMM -> 7x7 NATTEN (GQA 12q/4kv, D=64) -> out GEMM.
// 2048 pixels (2x32x32), d_model 768.
// Round 7: round-4 structure (separate convert; bf16 global_load_lds GEMM)
// + GEMM retiled 128Mx64N / BK=64 with double-buffered LDS and prefetch
// issued AFTER the barrier (drain at next barrier overlaps with compute).
// 48 KB LDS -> 3 blocks/CU. Natten unchanged.
// ---------------------------------------------------------------------------

typedef __attribute__((ext_vector_type(8))) __bf16 bf16x8;
typedef __attribute__((ext_vector_type(4))) float floatx4;
typedef unsigned short u16;

__device__ inline u16 f2bf(float f) {
    union { float f; unsigned u; } v; v.f = f;
    return (u16)((v.u + 0x7fff + ((v.u >> 16) & 1)) >> 16);   // RNE
}

__device__ inline void gl_lds16(const void* g, void* l) {
    __builtin_amdgcn_global_load_lds(
        (const __attribute__((address_space(1))) void*)g,
        (__attribute__((address_space(3))) void*)l, 16, 0, 0);
}

// fp32 -> bf16 for x (393216 f4), w_qkv (245760 f4), w_out (147456 f4).
__global__ __launch_bounds__(256) void convert_kernel(
    const float* __restrict__ x, const float* __restrict__ w1,
    const float* __restrict__ w2, u16* __restrict__ xb,
    u16* __restrict__ w1b, u16* __restrict__ w2b)
{
    int t = blockIdx.x * blockDim.x + threadIdx.x;   // 0..786431
    const float* s; u16* d;
    if (t < 393216)      { s = x;  d = xb; }
    else if (t < 638976) { s = w1; d = w1b; t -= 393216; }
    else                 { s = w2; d = w2b; t -= 638976; }
    float4 v = ((const float4*)s)[t];
    ushort4 o;
    o.x = f2bf(v.x); o.y = f2bf(v.y); o.z = f2bf(v.z); o.w = f2bf(v.w);
    ((ushort4*)d)[t] = o;
}

// C = A[M,K] @ B[N,K]^T, bf16 in, fp32 accum. Tile 128Mx64N, BK=64 staged as
// 2 kc sub-tiles of m97 layout [rows][32]. Double-buffered: prefetch for
// iter k+1 issued AFTER the barrier that publishes buf k, so the vmcnt drain
// at the NEXT barrier overlaps with this iter's MFMA section.
// 256 thr = 4 waves, wave quadrant 64x32 = 4x2 MFMA tiles of 16x16x32.
// Staging: 24 1KB-chunks/iter (A:16, B:8); wave w stages A{w,w+4,w+8,w+12},
// B{w,w+4}. Chunk = 16 rows x 32 k-elems; lane -> row lane>>2, oct lane&3.
// MODE 0: fp32 C[M,N]. MODE 1 (qkv): col<1024 -> bf16 Cb[row*1024+col];
// col>=1024 -> transposed bf16 vT[(col-1024)*2048 + row].
template<int MODE>
__global__ __launch_bounds__(256) void gemm_nt(
    const u16* __restrict__ A, const u16* __restrict__ B,
    float* __restrict__ C, u16* __restrict__ Cb, u16* __restrict__ vT,
    int N, int K)
{
    __shared__ __align__(16) u16 As[2][8192];   // [buf][kc*4096 + row*32] 32 KB
    __shared__ __align__(16) u16 Bs[2][4096];   // [buf][kc*2048 + row*32] 16 KB
    const int tid = threadIdx.x;
    const int lane = tid & 63;
    const int wave = tid >> 6;
    const int bm = blockIdx.y * 128;
    const int bn = blockIdx.x * 64;
    const int qr = (wave >> 1) * 64;
    const int qc = (wave & 1) * 32;

    floatx4 acc[4][2] = {};

    const int lrow = lane >> 2;          // 0..15 row within chunk
    const int loct = (lane & 3) * 8;     // k-oct within 32
    int gA[4], lA[4], gB[2], lB[2];
    #pragma unroll
    for (int i = 0; i < 4; i++) {
        int c = wave + 4 * i, kc = c & 1, rowg = c >> 1;
        gA[i] = (bm + rowg * 16 + lrow) * K + kc * 32 + loct;
        lA[i] = kc * 4096 + rowg * 512;
    }
    #pragma unroll
    for (int i = 0; i < 2; i++) {
        int c = wave + 4 * i, kc = c & 1, rowg = c >> 1;
        gB[i] = (bn + rowg * 16 + lrow) * K + kc * 32 + loct;
        lB[i] = kc * 2048 + rowg * 512;
    }

    const int fr = lane & 15;
    const int fk = (lane >> 4) * 8;
    const int nk = K >> 6;               // K/64

    // prologue: stage iter 0 into buf 0
    #pragma unroll
    for (int i = 0; i < 4; i++) gl_lds16(A + gA[i], &As[0][lA[i]]);
    #pragma unroll
    for (int i = 0; i < 2; i++) gl_lds16(B + gB[i], &Bs[0][lB[i]]);

    for (int it = 0; it < nk; it++) {
        __syncthreads();                 // publishes buf it&1 (vmcnt drained)
        if (it + 1 < nk) {               // prefetch AFTER barrier -> overlaps
            const int nb = (it + 1) & 1;
            const int ko = (it + 1) * 64;
            #pragma unroll
            for (int i = 0; i < 4; i++) gl_lds16(A + gA[i] + ko, &As[nb][lA[i]]);
            #pragma unroll
            for (int i = 0; i < 2; i++) gl_lds16(B + gB[i] + ko, &Bs[nb][lB[i]]);
        }
        const int b = it & 1;
        #pragma unroll
        for (int kc = 0; kc < 2; kc++) {
            bf16x8 af0 = *(const bf16x8*)&As[b][kc * 4096 + (qr +      fr) * 32 + fk];
            bf16x8 af1 = *(const bf16x8*)&As[b][kc * 4096 + (qr + 16 + fr) * 32 + fk];
            bf16x8 af2 = *(const bf16x8*)&As[b][kc * 4096 + (qr + 32 + fr) * 32 + fk];
            bf16x8 af3 = *(const bf16x8*)&As[b][kc * 4096 + (qr + 48 + fr) * 32 + fk];
            bf16x8 bf0 = *(const bf16x8*)&Bs[b][kc * 2048 + (qc +      fr) * 32 + fk];
            bf16x8 bf1 = *(const bf16x8*)&Bs[b][kc * 2048 + (qc + 16 + fr) * 32 + fk];
            acc[0][0] = __builtin_amdgcn_mfma_f32_16x16x32_bf16(af0, bf0, acc[0][0], 0, 0, 0);
            acc[0][1] = __builtin_amdgcn_mfma_f32_16x16x32_bf16(af0, bf1, acc[0][1], 0, 0, 0);
            acc[1][0] = __builtin_amdgcn_mfma_f32_16x16x32_bf16(af1, bf0, acc[1][0], 0, 0, 0);
            acc[1][1] = __builtin_amdgcn_mfma_f32_16x16x32_bf16(af1, bf1, acc[1][1], 0, 0, 0);
            acc[2][0] = __builtin_amdgcn_mfma_f32_16x16x32_bf16(af2, bf0, acc[2][0], 0, 0, 0);
            acc[2][1] = __builtin_amdgcn_mfma_f32_16x16x32_bf16(af2, bf1, acc[2][1], 0, 0, 0);
            acc[3][0] = __builtin_amdgcn_mfma_f32_16x16x32_bf16(af3, bf0, acc[3][0], 0, 0, 0);
            acc[3][1] = __builtin_amdgcn_mfma_f32_16x16x32_bf16(af3, bf1, acc[3][1], 0, 0, 0);
        }
    }

    // C/D layout: col = lane&15, row = (lane>>4)*4 + r.
    const int cr = (lane >> 4) * 4;
    const int ccol = lane & 15;
    #pragma unroll
    for (int i = 0; i < 4; i++) {
        #pragma unroll
        for (int j = 0; j < 2; j++) {
            const int row0 = bm + qr + i * 16 + cr;
            const int col  = bn + qc + j * 16 + ccol;
            if (MODE == 0) {
                #pragma unroll
                for (int r = 0; r < 4; r++)
                    C[(size_t)(row0 + r) * N + col] = acc[i][j][r];
            } else {
                if (col < 1024) {
                    #pragma unroll
                    for (int r = 0; r < 4; r++)
                        Cb[(size_t)(row0 + r) * 1024 + col] = f2bf(acc[i][j][r]);
                } else {
                    ushort4 w;
                    w.x = f2bf(acc[i][j][0]); w.y = f2bf(acc[i][j][1]);
                    w.z = f2bf(acc[i][j][2]); w.w = f2bf(acc[i][j][3]);
                    *(ushort4*)&vT[(size_t)(col - 1024) * 2048 + row0] = w;
                }
            }
        }
    }
}

// NATTEN 7x7 MFMA. Block = (q-head h, 8x8 pixel tile). 4 waves x 16 queries.
// KV union = 14x14 patch at wu = clip(tile-3, 0, 18); n = a*16+b, masked.
__global__ __launch_bounds__(256) void natten_mfma(
    const u16* __restrict__ qkv, const u16* __restrict__ vT,
    u16* __restrict__ o)
{
    __shared__ __align__(16) u16 Ks[224 * 72];
    __shared__ __align__(16) u16 Vs[64 * 224];
    __shared__ __align__(16) u16 Pw[4 * 512];
    const int h  = blockIdx.x;        // 0..11
    const int tb = blockIdx.y;        // 0..31
    const int g  = h & 3;
    const int batch = tb >> 4;
    const int ti = ((tb >> 2) & 3) * 8;
    const int tj = (tb & 3) * 8;
    const int wu_i = min(max(ti - 3, 0), 18);
    const int wu_j = min(max(tj - 3, 0), 18);
    const int tid = threadIdx.x, lane = tid & 63, wave = tid >> 6;
    const int pixbase = batch << 10;

    for (int c = tid; c < 1792; c += 256) {
        int n = c >> 3, seg = (c & 7) * 8;
        int a = n >> 4, b = min(n & 15, 13);
        int pix = pixbase + (wu_i + a) * 32 + wu_j + b;
        *(uint4*)&Ks[n * 72 + seg] =
            *(const uint4*)&qkv[(size_t)pix * 1024 + 768 + g * 64 + seg];
    }
    {
        const int b  = lane & 15;
        const int ar = lane >> 4;
        bool vok[4]; int voff[4];
        #pragma unroll
        for (int rr = 0; rr < 4; rr++) {
            int a = ar + rr * 4;
            vok[rr]  = (a < 14) && (b < 14);
            voff[rr] = (wu_i + a) * 32 + wu_j + b;
        }
        const u16* vsrc = &vT[(size_t)(g * 64 + wave * 16) * 2048 + pixbase];
        #pragma unroll 4
        for (int dd = 0; dd < 16; dd++) {
            #pragma unroll
            for (int rr = 0; rr < 4; rr++) {
                int a = ar + rr * 4;
                if (a < 14)
                    Vs[(wave * 16 + dd) * 224 + rr * 64 + lane] =
                        vok[rr] ? vsrc[voff[rr]] : (u16)0;
            }
            vsrc += 2048;
        }
    }
    __syncthreads();

    const int fr = lane & 15;
    const int fk = (lane >> 4) * 8;

    bf16x8 aq0, aq1;
    {
        int qq = wave * 16 + fr;
        int pixq = pixbase + (ti + (qq >> 3)) * 32 + tj + (qq & 7);
        const u16* qp = &qkv[(size_t)pixq * 1024 + h * 64];
        aq0 = *(const bf16x8*)(qp + fk);
        aq1 = *(const bf16x8*)(qp + 32 + fk);
    }

    bool colok[4]; int tlo[4], thi[4];
    #pragma unroll
    for (int r = 0; r < 4; r++) {
        int qq = wave * 16 + (lane >> 4) * 4 + r;
        int qi = ti + (qq >> 3), qj = tj + (qq & 7);
        int si = min(max(qi - 3, 0), 25);
        int sj = min(max(qj - 3, 0), 25);
        colok[r] = (fr < 14) && (wu_j + fr >= sj) && (wu_j + fr <= sj + 6);
        tlo[r] = si - wu_i; thi[r] = tlo[r] + 6;
    }

    float s[14][4];
    float mx[4] = {-1e30f, -1e30f, -1e30f, -1e30f};
    #pragma unroll
    for (int t = 0; t < 14; t++) {
        bf16x8 bk0 = *(const bf16x8*)&Ks[(t * 16 + fr) * 72 + fk];
        bf16x8 bk1 = *(const bf16x8*)&Ks[(t * 16 + fr) * 72 + 32 + fk];
        floatx4 a4 = {};
        a4 = __builtin_amdgcn_mfma_f32_16x16x32_bf16(aq0, bk0, a4, 0, 0, 0);
        a4 = __builtin_amdgcn_mfma_f32_16x16x32_bf16(aq1, bk1, a4, 0, 0, 0);
        #pragma unroll
        for (int r = 0; r < 4; r++) {
            bool v = colok[r] && (t >= tlo[r]) && (t <= thi[r]);
            s[t][r] = v ? a4[r] * 0.125f : -1e30f;
            mx[r] = fmaxf(mx[r], s[t][r]);
        }
    }
    #pragma unroll
    for (int r = 0; r < 4; r++) {
        mx[r] = fmaxf(mx[r], __shfl_xor(mx[r], 1));
        mx[r] = fmaxf(mx[r], __shfl_xor(mx[r], 2));
        mx[r] = fmaxf(mx[r], __shfl_xor(mx[r], 4));
        mx[r] = fmaxf(mx[r], __shfl_xor(mx[r], 8));
    }
    float l[4] = {0.f, 0.f, 0.f, 0.f};
    #pragma unroll
    for (int t = 0; t < 14; t++)
        #pragma unroll
        for (int r = 0; r < 4; r++) {
            float p = __expf(s[t][r] - mx[r]);
            s[t][r] = p; l[r] += p;
        }
    #pragma unroll
    for (int r = 0; r < 4; r++) {
        l[r] += __shfl_xor(l[r], 1);
        l[r] += __shfl_xor(l[r], 2);
        l[r] += __shfl_xor(l[r], 4);
        l[r] += __shfl_xor(l[r], 8);
    }
    float rinv[4];
    #pragma unroll
    for (int r = 0; r < 4; r++) rinv[r] = 1.0f / l[r];

    u16* pw = &Pw[wave * 512];
    floatx4 oacc[4] = {};
    #pragma unroll
    for (int kc = 0; kc < 7; kc++) {
        #pragma unroll
        for (int tt = 0; tt < 2; tt++) {
            int t = kc * 2 + tt;
            #pragma unroll
            for (int r = 0; r < 4; r++)
                pw[((lane >> 4) * 4 + r) * 32 + tt * 16 + fr] =
                    f2bf(s[t][r] * rinv[r]);
        }
        bf16x8 bp = *(const bf16x8*)&pw[fr * 32 + fk];
        #pragma unroll
        for (int u = 0; u < 4; u++) {
            bf16x8 av = *(const bf16x8*)&Vs[(u * 16 + fr) * 224 + kc * 32 + fk];
            oacc[u] = __builtin_amdgcn_mfma_f32_16x16x32_bf16(av, bp, oacc[u], 0, 0, 0);
        }
    }

    {
        int qq = wave * 16 + fr;
        int pixq = pixbase + (ti + (qq >> 3)) * 32 + tj + (qq & 7);
        u16* op = &o[(size_t)pixq * 768 + h * 64];
        #pragma unroll
        for (int u = 0; u < 4; u++) {
            ushort4 w;
            w.x = f2bf(oacc[u][0]); w.y = f2bf(oacc[u][1]);
            w.z = f2bf(oacc[u][2]); w.w = f2bf(oacc[u][3]);
            *(ushort4*)(op + u * 16 + (lane >> 4) * 4) = w;
        }
    }
}

extern "C" void kernel_launch(void* const* d_in, const int* in_sizes, int n_in,
                              void* d_out, int out_size, void* d_ws, size_t ws_size,
                              hipStream_t stream)
{
    const float* x     = (const float*)d_in[0];   // (2048, 768)
    const float* w_qkv = (const float*)d_in[1];   // (1280, 768)
    const float* w_out = (const float*)d_in[2];   // (768, 768)
    float* out = (float*)d_out;                   // (2048, 768) fp32

    char* ws = (char*)d_ws;
    u16* qkvb = (u16*)ws; ws += (size_t)2048 * 1024 * 2;     // q|k bf16, 4 MB
    u16* vTb  = (u16*)ws; ws += (size_t)256 * 2048 * 2;      // v^T bf16, 1 MB
    u16* xb   = (u16*)ws; ws += (size_t)2048 * 768 * 2;      // 3 MB
    u16* w1b  = (u16*)ws; ws += (size_t)1280 * 768 * 2;      // 2 MB
    u16* w2b  = (u16*)ws; ws += (size_t)768 * 768 * 2;       // 1.1 MB
    u16* ob   = (u16*)ws;                                    // 3 MB

    convert_kernel<<<dim3(3072), dim3(256), 0, stream>>>(x, w_qkv, w_out, xb, w1b, w2b);

    // qkv = x @ w_qkv^T -> bf16 q|k (cols<1024) + transposed v (cols>=1024)
    gemm_nt<1><<<dim3(1280 / 64, 2048 / 128), dim3(256), 0, stream>>>(
        xb, w1b, nullptr, qkvb, vTb, 1280, 768);

    natten_mfma<<<dim3(12, 32), dim3(256), 0, stream>>>(qkvb, vTb, ob);

    // out = o @ w_out^T (fp32 out)
    gemm_nt<0><<<dim3(768 / 64, 2048 / 128), dim3(256), 0, stream>>>(
        ob, w2b, out, nullptr, nullptr, 768, 768);
}